// Round 12
// baseline (323.231 us; speedup 1.0000x reference)
//
#include <hip/hip_runtime.h>

// ---------------------------------------------------------------------------
// AttentionActPrune — full MHA forward. B=4, S=2048, H=16, DH=64, D=1024.
// fp32 in/out; threshold 2% of max|ref| -> bf16 MFMA compute.
// Pipeline: cvt_all -> merged QKV GEMM (BK=64, swizzled LDS, Ts aliased;
// Q pre-scaled by softmax const; V -> Vt[bh][d][s] transposed epilogue) ->
// flash-attn (kv-permuted K staging -> K=32 PV MFMAs, register P, XCD
// swizzle, ping-pong LDS) -> GEMM out (BK=64, fp32).
// ---------------------------------------------------------------------------

typedef __bf16 bf16;
typedef __bf16 bf16x8 __attribute__((ext_vector_type(8)));
typedef __bf16 bf16x4 __attribute__((ext_vector_type(4)));
typedef float  floatx4 __attribute__((ext_vector_type(4)));

#define NB   4
#define SEQ  2048
#define NH   16
#define DH   64
#define DIM  1024
#define MTOT (NB * SEQ)   // 8192

#define CEXP 0.18033688f   // (1/sqrt(DH)) * log2(e), folded into Q

__device__ __forceinline__ floatx4 zero4() {
    floatx4 z; z[0] = 0.f; z[1] = 0.f; z[2] = 0.f; z[3] = 0.f; return z;
}

__device__ __forceinline__ void load_lds16(const bf16* g, bf16* l) {
    __builtin_amdgcn_global_load_lds(
        (__attribute__((address_space(1))) void*)g,
        (__attribute__((address_space(3))) void*)l,
        16, 0, 0);
}

// ---------------------------------------------------------------------------
// fp32 -> bf16 converts: X (MD elems) then [Wq;Wk;Wv;Wo] (4*DD) in one grid.
// ---------------------------------------------------------------------------
__global__ __launch_bounds__(256) void cvt_all(const float* __restrict__ X,
                                               const float* __restrict__ w0,
                                               const float* __restrict__ w1,
                                               const float* __restrict__ w2,
                                               const float* __restrict__ w3,
                                               bf16* __restrict__ Xb,
                                               bf16* __restrict__ Wb) {
    const size_t MD = (size_t)MTOT * DIM;
    const size_t DD = (size_t)DIM * DIM;   // 2^20
    size_t i = ((size_t)blockIdx.x * 256 + threadIdx.x) * 4;
    float4 f; bf16* dst;
    if (i < MD) {
        f = *(const float4*)(X + i);
        dst = Xb + i;
    } else {
        size_t off = i - MD;
        int w = (int)(off >> 20);
        size_t wi = off & (DD - 1);
        const float* ws = (w == 0) ? w0 : (w == 1) ? w1 : (w == 2) ? w2 : w3;
        f = *(const float4*)(ws + wi);
        dst = Wb + off;
    }
    bf16x4 o;
    o[0] = (bf16)f.x; o[1] = (bf16)f.y; o[2] = (bf16)f.z; o[3] = (bf16)f.w;
    *(bf16x4*)dst = o;
}

// ---------------------------------------------------------------------------
// Merged QKV GEMM, BK=64. W = [Wq;Wk;Wv;Wo] rows contiguous. blockIdx.x:
// 0-7 Q, 8-15 K, 16-23 V(transposed epilogue). C=A@W^T+b. Staging uses
// XOR-swizzled 16B chunks (row=c>>3, col8=(c&7)^(row&7)) so BK=64 fragment
// reads are <=2-way on banks. Ts (V transpose) ALIASES As/Bs — it's only
// live after the K-loop, so it costs no extra LDS (33.8 -> 32 KB).
// Q output (sel==0) additionally scaled by CEXP (softmax fold).
// ---------------------------------------------------------------------------
__global__ __launch_bounds__(256, 4) void gemm_qkv(const bf16* __restrict__ A,
                                                   const bf16* __restrict__ W,
                                                   const float* __restrict__ bq,
                                                   const float* __restrict__ bk,
                                                   const float* __restrict__ bv,
                                                   bf16* __restrict__ Qo,
                                                   bf16* __restrict__ Ko,
                                                   bf16* __restrict__ Vt) {
    __shared__ __align__(16) bf16 smem[2 * 128 * 64];   // As | Bs (32 KB)
    bf16* As = smem;              // 128 x 64, swizzled chunks
    bf16* Bs = smem + 128 * 64;
    bf16* Ts = smem;              // 64 x 136 epilogue buffer (17.4 KB alias)

    const int tid  = threadIdx.x;
    const int wave = tid >> 6, lane = tid & 63;
    const int quad = lane >> 4, l16 = lane & 15;
    const int sel = blockIdx.x >> 3;            // 0=Q 1=K 2=V
    const int nt  = blockIdx.x & 7;
    const int m0 = blockIdx.y * 128, n0 = nt * 128;
    const int wm = (wave & 1) * 64, wn = (wave >> 1) * 64;
    const bf16* Wsel = W + (size_t)(sel * DIM + n0) * DIM;
    const float* bias = (sel == 0) ? bq : (sel == 1) ? bk : bv;
    const float scale = (sel == 0) ? CEXP : 1.0f;

    // staging addresses (k0-invariant): 4 chunks per array per thread
    const bf16* ga[4]; const bf16* gb[4]; int cb[4];
#pragma unroll
    for (int i = 0; i < 4; i++) {
        cb[i] = wave * 256 + i * 64;
        const int c = cb[i] + lane;
        const int row = c >> 3;                 // 0..127
        const int col8 = (c & 7) ^ (row & 7);   // XOR swizzle
        ga[i] = A + (size_t)(m0 + row) * DIM + col8 * 8;
        gb[i] = Wsel + (size_t)row * DIM + col8 * 8;
    }

    floatx4 acc[4][4];
#pragma unroll
    for (int mi = 0; mi < 4; mi++)
#pragma unroll
        for (int ni = 0; ni < 4; ni++) acc[mi][ni] = zero4();

    for (int k0 = 0; k0 < DIM; k0 += 64) {
        __syncthreads();
#pragma unroll
        for (int i = 0; i < 4; i++) {
            load_lds16(ga[i] + k0, &As[cb[i] * 8]);
            load_lds16(gb[i] + k0, &Bs[cb[i] * 8]);
        }
        __syncthreads();

#pragma unroll
        for (int half = 0; half < 2; half++) {
            bf16x8 af[4], bfr[4];
#pragma unroll
            for (int mi = 0; mi < 4; mi++) {
                const int row = wm + mi * 16 + l16;
                af[mi] = *(const bf16x8*)
                    &As[(row * 8 + ((half * 4 + quad) ^ (row & 7))) * 8];
            }
#pragma unroll
            for (int ni = 0; ni < 4; ni++) {
                const int row = wn + ni * 16 + l16;
                bfr[ni] = *(const bf16x8*)
                    &Bs[(row * 8 + ((half * 4 + quad) ^ (row & 7))) * 8];
            }
#pragma unroll
            for (int mi = 0; mi < 4; mi++)
#pragma unroll
                for (int ni = 0; ni < 4; ni++)
                    acc[mi][ni] = __builtin_amdgcn_mfma_f32_16x16x32_bf16(
                        af[mi], bfr[ni], acc[mi][ni], 0, 0, 0);
        }
    }

    if (sel < 2) {
        bf16* C = (sel == 0) ? Qo : Ko;
#pragma unroll
        for (int mi = 0; mi < 4; mi++) {
            const int rbase = m0 + wm + mi * 16 + quad * 4;
#pragma unroll
            for (int ni = 0; ni < 4; ni++) {
                const int col = n0 + wn + ni * 16 + l16;
                const float bval = bias[col];
#pragma unroll
                for (int i = 0; i < 4; i++)
                    C[(size_t)(rbase + i) * DIM + col] =
                        (bf16)((acc[mi][ni][i] + bval) * scale);
            }
        }
    } else {
        // write Vt[(b*NH+h)][d][s] via LDS transpose (Ts aliases As/Bs:
        // first __syncthreads ensures all waves' K-loop LDS reads are done)
        const int b  = blockIdx.y >> 4;
        const int s0 = (blockIdx.y & 15) * 128;
#pragma unroll
        for (int r = 0; r < 2; r++) {
            __syncthreads();
            if ((wave >> 1) == r) {
#pragma unroll
                for (int mi = 0; mi < 4; mi++) {
                    const int m_l = wm + mi * 16 + quad * 4;
#pragma unroll
                    for (int ni = 0; ni < 4; ni++) {
                        const int n_loc = ni * 16 + l16;
                        const float bval = bias[n0 + 64 * r + n_loc];
#pragma unroll
                        for (int i = 0; i < 4; i++)
                            Ts[n_loc * 136 + m_l + i] = (bf16)(acc[mi][ni][i] + bval);
                    }
                }
            }
            __syncthreads();
            const int hh = 2 * nt + r;
            bf16* obase = Vt + ((size_t)(b * NH + hh) * DH) * SEQ + s0;
#pragma unroll
            for (int p = 0; p < 4; p++) {
                const int chunk = p * 256 + tid;
                const int row = chunk >> 4, c0 = (chunk & 15) * 8;
                bf16x8 v = *(const bf16x8*)&Ts[row * 136 + c0];
                *(bf16x8*)(obase + (size_t)row * SEQ + c0) = v;
            }
        }
    }
}

// ---------------------------------------------------------------------------
// Out-projection GEMM (fp32 out), 128x128 tiles, BK=64, swizzled staging.
// ---------------------------------------------------------------------------
__global__ __launch_bounds__(256, 4) void gemm_out(const bf16* __restrict__ A,
                                                   const bf16* __restrict__ W,
                                                   const float* __restrict__ bias,
                                                   float* __restrict__ C) {
    __shared__ __align__(16) bf16 smem[2 * 128 * 64];
    bf16* As = smem;
    bf16* Bs = smem + 128 * 64;

    const int tid  = threadIdx.x;
    const int wave = tid >> 6, lane = tid & 63;
    const int quad = lane >> 4, l16 = lane & 15;
    const int m0 = blockIdx.y * 128, n0 = blockIdx.x * 128;
    const int wm = (wave & 1) * 64, wn = (wave >> 1) * 64;

    const bf16* ga[4]; const bf16* gb[4]; int cb[4];
#pragma unroll
    for (int i = 0; i < 4; i++) {
        cb[i] = wave * 256 + i * 64;
        const int c = cb[i] + lane;
        const int row = c >> 3;
        const int col8 = (c & 7) ^ (row & 7);
        ga[i] = A + (size_t)(m0 + row) * DIM + col8 * 8;
        gb[i] = W + (size_t)(n0 + row) * DIM + col8 * 8;
    }

    floatx4 acc[4][4];
#pragma unroll
    for (int mi = 0; mi < 4; mi++)
#pragma unroll
        for (int ni = 0; ni < 4; ni++) acc[mi][ni] = zero4();

    for (int k0 = 0; k0 < DIM; k0 += 64) {
        __syncthreads();
#pragma unroll
        for (int i = 0; i < 4; i++) {
            load_lds16(ga[i] + k0, &As[cb[i] * 8]);
            load_lds16(gb[i] + k0, &Bs[cb[i] * 8]);
        }
        __syncthreads();

#pragma unroll
        for (int half = 0; half < 2; half++) {
            bf16x8 af[4], bfr[4];
#pragma unroll
            for (int mi = 0; mi < 4; mi++) {
                const int row = wm + mi * 16 + l16;
                af[mi] = *(const bf16x8*)
                    &As[(row * 8 + ((half * 4 + quad) ^ (row & 7))) * 8];
            }
#pragma unroll
            for (int ni = 0; ni < 4; ni++) {
                const int row = wn + ni * 16 + l16;
                bfr[ni] = *(const bf16x8*)
                    &Bs[(row * 8 + ((half * 4 + quad) ^ (row & 7))) * 8];
            }
#pragma unroll
            for (int mi = 0; mi < 4; mi++)
#pragma unroll
                for (int ni = 0; ni < 4; ni++)
                    acc[mi][ni] = __builtin_amdgcn_mfma_f32_16x16x32_bf16(
                        af[mi], bfr[ni], acc[mi][ni], 0, 0, 0);
        }
    }

#pragma unroll
    for (int mi = 0; mi < 4; mi++) {
        const int rbase = m0 + wm + mi * 16 + quad * 4;
#pragma unroll
        for (int ni = 0; ni < 4; ni++) {
            const int col = n0 + wn + ni * 16 + l16;
            const float bval = bias[col];
#pragma unroll
            for (int i = 0; i < 4; i++)
                C[(size_t)(rbase + i) * DIM + col] = acc[mi][ni][i] + bval;
        }
    }
}

// ---------------------------------------------------------------------------
// Flash attention (unchanged from round 11): 4-wave blocks = 128 q rows of
// one (b,h), 32 q/wave, XCD-swizzled grid, kv-permuted K staging -> K=32 PV
// MFMAs, register-resident P, ping-pong LDS, Q pre-scaled -> P = exp2(z).
// ---------------------------------------------------------------------------
__global__ __launch_bounds__(256, 4) void attn_kernel(const bf16* __restrict__ Q,
                                                      const bf16* __restrict__ K,
                                                      const bf16* __restrict__ Vt,
                                                      bf16* __restrict__ Ctx) {
    __shared__ __align__(16) bf16 Ks[2][64 * 64];  // swizzled, kv-permuted
    __shared__ __align__(16) bf16 Vs[2][64 * 64];  // swizzled, natural order

    const int tid  = threadIdx.x;
    const int wave = tid >> 6, lane = tid & 63;
    const int quad = lane >> 4, l16 = lane & 15;
    const int xcd = blockIdx.x & 7;
    const int j   = blockIdx.x >> 3;        // 0..127
    const int bh  = xcd * 8 + (j >> 4);     // b*NH + h
    const int qb  = j & 15;                 // 128-row q block
    const int b   = bh >> 4, h = bh & 15;

    const size_t base_bh = (size_t)b * SEQ * DIM + (size_t)h * DH;
    const size_t base_v  = (size_t)bh * DH * SEQ;
    const int qt = qb * 128 + wave * 32;    // wave's 32 q rows

    bf16x8 aq[2][2];
#pragma unroll
    for (int m = 0; m < 2; m++) {
        const bf16* qp = Q + base_bh + (size_t)(qt + m * 16 + l16) * DIM + quad * 8;
        aq[m][0] = *(const bf16x8*)qp;
        aq[m][1] = *(const bf16x8*)(qp + 32);
    }

    const int sc = wave * 128 + lane;
    int srow[2], scol[2];
    srow[0] = sc >> 3;        srow[1] = (sc + 64) >> 3;
    scol[0] = (sc & 7) ^ (srow[0] & 7);
    scol[1] = ((sc + 64) & 7) ^ (srow[1] & 7);
    auto kvloc = [](int r) {
        const int w = r >> 5, rw = r & 31, r4 = rw & 15;
        return w * 32 + ((rw >> 4) << 2) + ((r4 >> 2) << 3) + (r4 & 3);
    };
    const bf16* kga = K + base_bh + (size_t)kvloc(srow[0]) * DIM + scol[0] * 8;
    const bf16* kgb = K + base_bh + (size_t)kvloc(srow[1]) * DIM + scol[1] * 8;
    const bf16* vga = Vt + base_v + (size_t)srow[0] * SEQ + scol[0] * 8;
    const bf16* vgb = Vt + base_v + (size_t)srow[1] * SEQ + scol[1] * 8;
    const int ldsa = (wave * 128) * 8, ldsb = (wave * 128 + 64) * 8;

    int koa[4], kob[4], vo[2][4];
#pragma unroll
    for (int g = 0; g < 4; g++) {
        const int krow = g * 16 + l16;
        koa[g] = (krow * 8 + (quad ^ (krow & 7))) * 8;
        kob[g] = (krow * 8 + ((4 + quad) ^ (krow & 7))) * 8;
    }
#pragma unroll
    for (int w = 0; w < 2; w++)
#pragma unroll
        for (int dt = 0; dt < 4; dt++) {
            const int d = dt * 16 + l16;
            vo[w][dt] = d * 64 + ((4 * w + quad) ^ (d & 7)) * 8;
        }

    bf16x8 ones8;
#pragma unroll
    for (int i = 0; i < 8; i++) ones8[i] = (bf16)1.0f;

    floatx4 acc[2][4], accl[2];
#pragma unroll
    for (int m = 0; m < 2; m++) {
        accl[m] = zero4();
#pragma unroll
        for (int dt = 0; dt < 4; dt++) acc[m][dt] = zero4();
    }

    load_lds16(kga, &Ks[0][ldsa]);
    load_lds16(kgb, &Ks[0][ldsb]);
    load_lds16(vga, &Vs[0][ldsa]);
    load_lds16(vgb, &Vs[0][ldsb]);

    for (int it = 0; it < SEQ / 64; it++) {
        __syncthreads();
        const int cur = it & 1;
        if (it + 1 < SEQ / 64) {
            const int nxt = cur ^ 1;
            const size_t kvn = (size_t)(it + 1) * 64;
            load_lds16(kga + kvn * DIM, &Ks[nxt][ldsa]);
            load_lds16(kgb + kvn * DIM, &Ks[nxt][ldsb]);
            load_lds16(vga + kvn, &Vs[nxt][ldsa]);
            load_lds16(vgb + kvn, &Vs[nxt][ldsb]);
        }

#pragma unroll
        for (int w = 0; w < 2; w++) {
            const bf16x8 ke0 = *(const bf16x8*)&Ks[cur][koa[2 * w]];
            const bf16x8 ke1 = *(const bf16x8*)&Ks[cur][kob[2 * w]];
            const bf16x8 ko0 = *(const bf16x8*)&Ks[cur][koa[2 * w + 1]];
            const bf16x8 ko1 = *(const bf16x8*)&Ks[cur][kob[2 * w + 1]];
            bf16x8 pw[2];
#pragma unroll
            for (int m = 0; m < 2; m++) {
                floatx4 sa = zero4(), sb = zero4();
                sa = __builtin_amdgcn_mfma_f32_16x16x32_bf16(ke0, aq[m][0], sa, 0, 0, 0);
                sa = __builtin_amdgcn_mfma_f32_16x16x32_bf16(ke1, aq[m][1], sa, 0, 0, 0);
                sb = __builtin_amdgcn_mfma_f32_16x16x32_bf16(ko0, aq[m][0], sb, 0, 0, 0);
                sb = __builtin_amdgcn_mfma_f32_16x16x32_bf16(ko1, aq[m][1], sb, 0, 0, 0);
                bf16x8 p;
#pragma unroll
                for (int i = 0; i < 4; i++) {
                    p[i]     = (bf16)__builtin_amdgcn_exp2f(sa[i]);
                    p[4 + i] = (bf16)__builtin_amdgcn_exp2f(sb[i]);
                }
                pw[m] = p;
            }
            bf16x8 vf[4];
#pragma unroll
            for (int dt = 0; dt < 4; dt++)
                vf[dt] = *(const bf16x8*)&Vs[cur][vo[w][dt]];
#pragma unroll
            for (int m = 0; m < 2; m++) {
#pragma unroll
                for (int dt = 0; dt < 4; dt++)
                    acc[m][dt] = __builtin_amdgcn_mfma_f32_16x16x32_bf16(
                        pw[m], vf[dt], acc[m][dt], 0, 0, 0);
                accl[m] = __builtin_amdgcn_mfma_f32_16x16x32_bf16(
                    pw[m], ones8, accl[m], 0, 0, 0);
            }
        }
    }

#pragma unroll
    for (int m = 0; m < 2; m++) {
        float inv[4];
#pragma unroll
        for (int i = 0; i < 4; i++) inv[i] = 1.0f / accl[m][i];
        bf16* cp = Ctx + base_bh + (size_t)(qt + m * 16 + quad * 4) * DIM + l16;
#pragma unroll
        for (int i = 0; i < 4; i++)
#pragma unroll
            for (int dt = 0; dt < 4; dt++)
                cp[(size_t)i * DIM + dt * 16] = (bf16)(acc[m][dt][i] * inv[i]);
    }
}

// ---------------------------------------------------------------------------
extern "C" void kernel_launch(void* const* d_in, const int* in_sizes, int n_in,
                              void* d_out, int out_size, void* d_ws, size_t ws_size,
                              hipStream_t stream) {
    const float* X  = (const float*)d_in[0];
    const float* Wq = (const float*)d_in[1];
    const float* bq = (const float*)d_in[2];
    const float* Wk = (const float*)d_in[3];
    const float* bk = (const float*)d_in[4];
    const float* Wv = (const float*)d_in[5];
    const float* bv = (const float*)d_in[6];
    const float* Wo = (const float*)d_in[7];
    const float* bo = (const float*)d_in[8];
    float* out = (float*)d_out;

    const size_t MD = (size_t)MTOT * DIM;
    const size_t DD = (size_t)DIM * DIM;

    bf16* Xb  = (bf16*)d_ws;     // X bf16; reused as ctx after attention
    bf16* Qb  = Xb + MD;
    bf16* Kb  = Qb + MD;
    bf16* Vtb = Kb + MD;         // V transposed [B*H][DH][SEQ]
    bf16* Wqb = Vtb + MD;        // [Wq;Wk;Wv;Wo] rows contiguous
    bf16* Wob = Wqb + 3 * DD;
    if (ws_size < (MD * 4 + DD * 4) * sizeof(bf16)) return;

    cvt_all<<<(int)((MD + 4 * DD) / 4 / 256), 256, 0, stream>>>(
        X, Wq, Wk, Wv, Wo, Xb, Wqb);

    gemm_qkv<<<dim3(24, MTOT / 128), 256, 0, stream>>>(Xb, Wqb, bq, bk, bv,
                                                       Qb, Kb, Vtb);

    // 1024 blocks x 256 threads: XCD-swizzled 64 (b,h) x 16 q-blocks
    attn_kernel<<<NB * NH * (SEQ / 128), 256, 0, stream>>>(Qb, Kb, Vtb, Xb);

    gemm_out<<<dim3(8, MTOT / 128), 256, 0, stream>>>(Xb, Wob, bo, out);
}